// Round 1
// baseline (15586.266 us; speedup 1.0000x reference)
//
#include <hip/hip_runtime.h>

#define T_STEPS 512
#define B_ROWS  64
#define F_DIM   256
#define U_DIM   1024
#define G3      3072   // 3*U

typedef __bf16 bf16x8 __attribute__((ext_vector_type(8)));
typedef float  f32x4  __attribute__((ext_vector_type(4)));

__device__ __forceinline__ float sigmoidf_(float v) {
    return 1.f / (1.f + __expf(-v));
}
__device__ __forceinline__ float tanhf_(float v) {
    float e2 = __expf(2.f * v);
    return 1.f - 2.f / (e2 + 1.f);
}

// ---------------------------------------------------------------------------
// Transpose + cvt: src [Kdim][3072] f32  ->  dst [3072][Kdim] bf16
// ---------------------------------------------------------------------------
__global__ __launch_bounds__(256) void transpose_cvt_kernel(
    const float* __restrict__ src, __bf16* __restrict__ dst, int Kdim)
{
    __shared__ float tile[32][33];
    const int n0 = blockIdx.x * 32;
    const int k0 = blockIdx.y * 32;
    const int j  = threadIdx.x & 31;
    const int i0 = threadIdx.x >> 5;   // 0..7
#pragma unroll
    for (int s = 0; s < 4; ++s) {
        int i = i0 * 4 + s;
        tile[i][j] = src[(size_t)(k0 + i) * G3 + n0 + j];
    }
    __syncthreads();
#pragma unroll
    for (int s = 0; s < 4; ++s) {
        int i = i0 * 4 + s;
        dst[(size_t)(n0 + i) * Kdim + k0 + j] = (__bf16)tile[j][i];
    }
}

// ---------------------------------------------------------------------------
// One GRU step. Grid: 64 blocks (16 u-columns each) x 256 threads (4 waves).
// Wave w computes rows [16w,16w+16) x 16 u's x {z,r,h} via mfma 16x16x32 bf16.
// A-frag: lane holds A[row = l&15][k = (l>>4)*8 + e]  (8 consecutive k -> b128)
// B-frag: lane holds B[k = (l>>4)*8 + e][col = l&15]  (Kt/Rt stored [col][k])
// C/D   : col = l&15, row = (l>>4)*4 + j              (verified layout)
// ---------------------------------------------------------------------------
__global__ __launch_bounds__(256) void gru_step_kernel(
    const float* __restrict__ x,      // [64][512][256] f32
    const float* __restrict__ hsrc,   // h_prev f32, row stride = hstride
    int hstride,
    const float* __restrict__ bias,   // [2][3072] f32
    const __bf16* __restrict__ Kt,    // [3072][256] bf16 (transposed kernel)
    const __bf16* __restrict__ Rt,    // [3072][1024] bf16 (transposed rec kernel)
    float* __restrict__ out,          // [64][512][1024] f32
    int t)
{
    const int lane = threadIdx.x & 63;
    const int wave = threadIdx.x >> 6;
    const int rc   = lane & 15;
    const int kg   = lane >> 4;
    const int row0 = wave << 4;
    const int u    = (blockIdx.x << 4) + rc;

    f32x4 accZ  = {0.f, 0.f, 0.f, 0.f};
    f32x4 accR  = {0.f, 0.f, 0.f, 0.f};
    f32x4 accHX = {0.f, 0.f, 0.f, 0.f};  // x-side of h-gate (outside r)
    f32x4 accHR = {0.f, 0.f, 0.f, 0.f};  // rec-side of h-gate (inside r)

    const int arow = row0 + rc;

    // ---- X phase: K = 256, A = x[arow, t, :], B = Kt ----
    {
        const float*  ap = x  + ((size_t)arow * T_STEPS + t) * F_DIM + (kg << 3);
        const __bf16* bz = Kt + ((size_t)(0 * U_DIM + u)) * F_DIM + (kg << 3);
        const __bf16* br = Kt + ((size_t)(1 * U_DIM + u)) * F_DIM + (kg << 3);
        const __bf16* bh = Kt + ((size_t)(2 * U_DIM + u)) * F_DIM + (kg << 3);
#pragma unroll
        for (int k0 = 0; k0 < F_DIM; k0 += 32) {
            const float4 a0 = *(const float4*)(ap + k0);
            const float4 a1 = *(const float4*)(ap + k0 + 4);
            bf16x8 af;
            af[0] = (__bf16)a0.x; af[1] = (__bf16)a0.y;
            af[2] = (__bf16)a0.z; af[3] = (__bf16)a0.w;
            af[4] = (__bf16)a1.x; af[5] = (__bf16)a1.y;
            af[6] = (__bf16)a1.z; af[7] = (__bf16)a1.w;
            accZ  = __builtin_amdgcn_mfma_f32_16x16x32_bf16(af, *(const bf16x8*)(bz + k0), accZ,  0, 0, 0);
            accR  = __builtin_amdgcn_mfma_f32_16x16x32_bf16(af, *(const bf16x8*)(br + k0), accR,  0, 0, 0);
            accHX = __builtin_amdgcn_mfma_f32_16x16x32_bf16(af, *(const bf16x8*)(bh + k0), accHX, 0, 0, 0);
        }
    }

    // ---- H phase: K = 1024, A = h_prev[arow, :], B = Rt ----
    {
        const float*  ap = hsrc + (size_t)arow * hstride + (kg << 3);
        const __bf16* bz = Rt + ((size_t)(0 * U_DIM + u)) * U_DIM + (kg << 3);
        const __bf16* br = Rt + ((size_t)(1 * U_DIM + u)) * U_DIM + (kg << 3);
        const __bf16* bh = Rt + ((size_t)(2 * U_DIM + u)) * U_DIM + (kg << 3);
#pragma unroll 4
        for (int k0 = 0; k0 < U_DIM; k0 += 32) {
            const float4 a0 = *(const float4*)(ap + k0);
            const float4 a1 = *(const float4*)(ap + k0 + 4);
            bf16x8 af;
            af[0] = (__bf16)a0.x; af[1] = (__bf16)a0.y;
            af[2] = (__bf16)a0.z; af[3] = (__bf16)a0.w;
            af[4] = (__bf16)a1.x; af[5] = (__bf16)a1.y;
            af[6] = (__bf16)a1.z; af[7] = (__bf16)a1.w;
            accZ  = __builtin_amdgcn_mfma_f32_16x16x32_bf16(af, *(const bf16x8*)(bz + k0), accZ,  0, 0, 0);
            accR  = __builtin_amdgcn_mfma_f32_16x16x32_bf16(af, *(const bf16x8*)(br + k0), accR,  0, 0, 0);
            accHR = __builtin_amdgcn_mfma_f32_16x16x32_bf16(af, *(const bf16x8*)(bh + k0), accHR, 0, 0, 0);
        }
    }

    // ---- epilogue: gates in f32, exact f32 carry ----
    const float bz_  = bias[u]             + bias[G3 + u];
    const float br_  = bias[U_DIM + u]     + bias[G3 + U_DIM + u];
    const float bhx  = bias[2 * U_DIM + u];
    const float bhr  = bias[G3 + 2 * U_DIM + u];
#pragma unroll
    for (int j = 0; j < 4; ++j) {
        const int row = row0 + (kg << 2) + j;
        const float z  = sigmoidf_(accZ[j] + bz_);
        const float r  = sigmoidf_(accR[j] + br_);
        const float hh = tanhf_(accHX[j] + bhx + r * (accHR[j] + bhr));
        const float hp = hsrc[(size_t)row * hstride + u];
        const float hn = z * hp + (1.f - z) * hh;
        out[((size_t)row * T_STEPS + t) * U_DIM + u] = hn;
    }
}

// ---------------------------------------------------------------------------
// Copy final state out[:, T-1, :] -> state region (appended after output)
// ---------------------------------------------------------------------------
__global__ __launch_bounds__(256) void copy_state_kernel(float* __restrict__ out)
{
    const int b = blockIdx.x;
    float* state = out + (size_t)B_ROWS * T_STEPS * U_DIM;
    for (int u = threadIdx.x; u < U_DIM; u += 256) {
        state[(size_t)b * U_DIM + u] =
            out[((size_t)b * T_STEPS + (T_STEPS - 1)) * U_DIM + u];
    }
}

extern "C" void kernel_launch(void* const* d_in, const int* in_sizes, int n_in,
                              void* d_out, int out_size, void* d_ws, size_t ws_size,
                              hipStream_t stream)
{
    const float* x      = (const float*)d_in[0];  // [64,512,256]
    const float* hidden = (const float*)d_in[1];  // [64,1024]
    const float* kernel = (const float*)d_in[2];  // [256,3072]
    const float* rker   = (const float*)d_in[3];  // [1024,3072]
    const float* bias   = (const float*)d_in[4];  // [2,3072]
    float* out = (float*)d_out;

    __bf16* Kt = (__bf16*)d_ws;                   // [3072][256]
    __bf16* Rt = Kt + (size_t)G3 * F_DIM;         // [3072][1024]

    // Prep: transpose+convert weights to bf16 [col][k]
    hipLaunchKernelGGL(transpose_cvt_kernel, dim3(G3 / 32, F_DIM / 32), dim3(256),
                       0, stream, kernel, Kt, F_DIM);
    hipLaunchKernelGGL(transpose_cvt_kernel, dim3(G3 / 32, U_DIM / 32), dim3(256),
                       0, stream, rker, Rt, U_DIM);

    // Sequential GRU steps; h lives in the output slices (f32 exact carry).
    for (int t = 0; t < T_STEPS; ++t) {
        const float* hsrc = (t == 0) ? hidden
                                     : out + (size_t)(t - 1) * U_DIM;
        const int hstride = (t == 0) ? U_DIM : T_STEPS * U_DIM;
        hipLaunchKernelGGL(gru_step_kernel, dim3(U_DIM / 16), dim3(256), 0, stream,
                           x, hsrc, hstride, bias, Kt, Rt, out, t);
    }

    hipLaunchKernelGGL(copy_state_kernel, dim3(B_ROWS), dim3(256), 0, stream, out);
}